// Round 7
// baseline (251.821 us; speedup 1.0000x reference)
//
#include <hip/hip_runtime.h>

// B=4, T=2048, C=1024, H=16, D=64. fp32 in/out, bf16 internal compute.

typedef unsigned short u16;
typedef unsigned int u32;
typedef __attribute__((ext_vector_type(8))) unsigned short u16x8;
typedef __attribute__((ext_vector_type(4))) unsigned short u16x4;
typedef __attribute__((ext_vector_type(8))) short short8;
typedef __attribute__((ext_vector_type(4))) float f32x4;

__device__ inline u16 f2bf(float f) {
  unsigned u = __float_as_uint(f);
  u = (u + 0x7FFF + ((u >> 16) & 1)) >> 16;  // RNE
  return (u16)u;
}

__device__ inline u16x8 cvt8(float4 a, float4 b) {
  u16x8 o;
  o[0] = f2bf(a.x); o[1] = f2bf(a.y); o[2] = f2bf(a.z); o[3] = f2bf(a.w);
  o[4] = f2bf(b.x); o[5] = f2bf(b.y); o[6] = f2bf(b.z); o[7] = f2bf(b.w);
  return o;
}

__device__ inline f32x4 mfma16(short8 a, short8 b, f32x4 c) {
  return __builtin_amdgcn_mfma_f32_16x16x32_bf16(a, b, c, 0, 0, 0);
}

// ---------- prep: weight transposes only (x is consumed fp32 by gemm1) ------
// Blocks [0,768): W_attn [1024][3072] -> wta [3072][1024] bf16 (48 x 16 tiles)
// Blocks [768,1024): W_proj [1024][1024] -> wtp [1024][1024] bf16 (16 x 16)
__device__ inline void tw_tile(const float* __restrict__ in,
                               u16* __restrict__ outT, int R, int Cc,
                               int c0, int r0, int tid, u16 (*t)[65]) {
  int a = tid & 63, w = tid >> 6;
#pragma unroll
  for (int j = 0; j < 16; ++j) {
    int r = w + j * 4;
    t[r][a] = f2bf(in[(size_t)(r0 + r) * Cc + c0 + a]);
  }
  __syncthreads();
#pragma unroll
  for (int j = 0; j < 16; ++j) {
    int c = w + j * 4;
    outT[(size_t)(c0 + c) * R + r0 + a] = t[a][c];
  }
}

__global__ __launch_bounds__(256) void k_prep(const float* __restrict__ Wa,
                                              u16* __restrict__ wta,
                                              const float* __restrict__ Wp,
                                              u16* __restrict__ wtp) {
  __shared__ u16 t[64][65];
  const int id = blockIdx.x, tid = threadIdx.x;
  if (id < 768) {
    tw_tile(Wa, wta, 1024, 3072, (id % 48) * 64, (id / 48) * 64, tid, t);
  } else {
    int q = id - 768;
    tw_tile(Wp, wtp, 1024, 1024, (q % 16) * 64, (q / 16) * 64, tid, t);
  }
}

// ---- bf16 GEMM: A[M][K] x Bt[N][K] + bias -> bf16 or fp32 out ----
// 128x128 block tile, BK=64, register-staged prefetch (proven structure).
// Block remap (bijective): XCD-chunk then 8-wide-m supertile.
// AF32=1: A is fp32 (x); converted to bf16 in registers during staging
// (bit-identical f2bf) — removes the separate x-convert pass entirely.
// VT=1: columns >= 2048 (V slice of qkv) written directly transposed into
// vt[b][h][d][t] as packed u16x4; the qkv V-slice write is skipped.
template <int OUTBF, int QSCALE, int VT, int AF32>
__global__ __launch_bounds__(256) void gemm_bt(const u16* __restrict__ A,
                                               const float* __restrict__ Af,
                                               const u16* __restrict__ Bt,
                                               const float* __restrict__ bias,
                                               u16* __restrict__ outb,
                                               float* __restrict__ outf,
                                               u16* __restrict__ vtout,
                                               int M, int N, int K) {
  __shared__ u16 As[128 * 64];
  __shared__ u16 Bs[128 * 64];
  const int nx = gridDim.x, ny = gridDim.y;
  int id0 = blockIdx.x + blockIdx.y * nx;
  int nwg = nx * ny;
  int q8 = nwg >> 3, x8 = id0 & 7, c8 = id0 >> 3;
  int id = x8 * q8 + c8;                    // nwg % 8 == 0 (bijective)
  int gs = 8 * ny, grp = id / gs, rem = id % gs;  // nx % 8 == 0
  const int m0 = (grp * 8 + (rem & 7)) * 128, n0 = (rem >> 3) * 128;

  const int tid = threadIdx.x, wave = tid >> 6, lane = tid & 63;
  const int quad = lane >> 4, l16 = lane & 15;
  const int wm = (wave & 1) * 64, wn = (wave >> 1) * 64;
  const int lrow = lane >> 3;      // 0..7 within the 8-row slab
  const int lch = lane & 7;        // global 16B chunk within the row
  const int slot = lch ^ lrow;     // swizzled LDS chunk slot
  const u16* sA[4];
  const float* sAf[4];
  const u16* sB[4];
  int offA[4], offB[4];
#pragma unroll
  for (int j = 0; j < 4; ++j) {
    int r = wave * 32 + j * 8;     // slab base row (multiple of 8)
    if (AF32)
      sAf[j] = Af + (size_t)(m0 + r + lrow) * K + lch * 8;
    else
      sA[j] = A + (size_t)(m0 + r + lrow) * K + lch * 8;
    sB[j] = Bt + (size_t)(n0 + r + lrow) * K + lch * 8;
    offA[j] = (r + lrow) * 64 + slot * 8;
    offB[j] = offA[j];
  }
  // prologue: load tile 0 into regs
  u16x8 ra[4], rb[4];
#pragma unroll
  for (int j = 0; j < 4; ++j) {
    if (AF32) {
      float4 a0 = *(const float4*)(sAf[j]);
      float4 a1 = *(const float4*)(sAf[j] + 4);
      ra[j] = cvt8(a0, a1);
    } else {
      ra[j] = *(const u16x8*)(sA[j]);
    }
    rb[j] = *(const u16x8*)(sB[j]);
  }
  f32x4 acc[4][4] = {};
  for (int kt = 0; kt < K; kt += 64) {
    __syncthreads();  // all waves done reading LDS tile kt-1
#pragma unroll
    for (int j = 0; j < 4; ++j) {
      *(u16x8*)&As[offA[j]] = ra[j];
      *(u16x8*)&Bs[offB[j]] = rb[j];
    }
    __syncthreads();
    if (kt + 64 < K) {  // prefetch tile kt+1 (latency hides under compute)
#pragma unroll
      for (int j = 0; j < 4; ++j) {
        if (AF32) {
          float4 a0 = *(const float4*)(sAf[j] + kt + 64);
          float4 a1 = *(const float4*)(sAf[j] + kt + 68);
          ra[j] = cvt8(a0, a1);
        } else {
          ra[j] = *(const u16x8*)(sA[j] + kt + 64);
        }
        rb[j] = *(const u16x8*)(sB[j] + kt + 64);
      }
    }
    const int sl = l16 & 7;
#pragma unroll
    for (int ks = 0; ks < 2; ++ks) {
      short8 af[4], bf[4];
#pragma unroll
      for (int mt = 0; mt < 4; ++mt)
        af[mt] = *(const short8*)(As + (wm + mt * 16 + l16) * 64 +
                                  ((ks * 4 + quad) ^ sl) * 8);
#pragma unroll
      for (int nt = 0; nt < 4; ++nt)
        bf[nt] = *(const short8*)(Bs + (wn + nt * 16 + l16) * 64 +
                                  ((ks * 4 + quad) ^ sl) * 8);
#pragma unroll
      for (int mt = 0; mt < 4; ++mt)
#pragma unroll
        for (int nt = 0; nt < 4; ++nt)
          acc[mt][nt] = mfma16(af[mt], bf[nt], acc[mt][nt]);
    }
  }
#pragma unroll
  for (int nt = 0; nt < 4; ++nt) {
    int col = n0 + wn + nt * 16 + l16;
    float bv = bias[col];
    if (VT && col >= 2048) {
      // V slice -> vt[(b*16+h)*64+d][t], hd = h*64+d = col-2048
      const int hd = col - 2048;
#pragma unroll
      for (int mt = 0; mt < 4; ++mt) {
        int rowb = m0 + wm + mt * 16 + quad * 4;  // global m, multiple of 4
        int bb = rowb >> 11, t0 = rowb & 2047;    // tile never crosses b
        u16x4 pk;
#pragma unroll
        for (int r = 0; r < 4; ++r) pk[r] = f2bf(acc[mt][nt][r] + bv);
        *(u16x4*)(vtout + ((size_t)(bb << 10) + hd) * 2048 + t0) = pk;
      }
    } else {
#pragma unroll
      for (int mt = 0; mt < 4; ++mt) {
        int rowb = m0 + wm + mt * 16 + quad * 4;
#pragma unroll
        for (int r = 0; r < 4; ++r) {
          float v = acc[mt][nt][r] + bv;
          if (QSCALE && col < 1024) v *= 0.18033688f;  // 0.125 * log2(e)
          if (OUTBF)
            outb[(size_t)(rowb + r) * N + col] = f2bf(v);
          else
            outf[(size_t)(rowb + r) * N + col] = v;
        }
      }
    }
  }
}

// ----------------- fused causal flash attention -------------------
// grid (8, H, B): block p handles 128-row q-tiles {p, 15-p} → uniform 34
// k-tiles/block, exactly 2 blocks/CU (proven optimum for this body).
// NEW: K/V double-buffered in LDS -> ONE barrier per k-tile (was two).
// Per iter kt: [kt>0: barrier] — retires all reads of buf[(kt-1)&1] and
// publishes iter kt-1's writes of buf[kt&1]; then ds_write tile kt+1 into
// the idle buffer buf[(kt+1)&1] (overlaps following compute); issue global
// loads for tile kt+2; compute tile kt from buf[kt&1]. Race-free: buffer
// (kt+1)&1 was last read in iter kt-1, whose readers all passed this
// iter's barrier. LDS 55.3 KB -> still 2 blocks/CU.
// Each wave owns TWO 16-row q-groups; fixed-reference softmax (Q
// pre-scaled by 0.125*log2e in gemm1); l on the MFMA pipe (P·ones).
// Group-0 diagonal at nkt-2; skips nkt-1.
// LDS: P aliases the 128-row Q region (wave-private rows, in-order DS).
#define ATP 72  // LDS row stride (elems): 144B = 9x16B, conflict-light
__global__ __launch_bounds__(256) void attn(const u16* __restrict__ qkv,
                                            const u16* __restrict__ vt,
                                            u16* __restrict__ y) {
  __shared__ u16 shm[384 * ATP];  // 55.3 KB
  u16* Qs = shm;                  // 128 rows; aliased as P after frag reads
  // K/V buffers: buf b at rows 128+128b (K: 64 rows, then V: 64 rows)
  const int p = blockIdx.x, h = blockIdx.y, b = blockIdx.z;
  const int tid = threadIdx.x, wave = tid >> 6, lane = tid & 63;
  const int quad = lane >> 4, l16 = lane & 15;
  const u16* Qg = qkv + (size_t)b * 2048 * 3072 + h * 64;
  const u16* Kg = Qg + 1024;
  const u16* Vtg = vt + (size_t)(b * 16 + h) * 64 * 2048;
  const int srow0 = tid >> 3, scol0 = (tid & 7) * 8;  // srow0 in [0,32)
  u16* Pw0 = Qs + (wave * 16) * ATP;        // group-0 P (wave-private rows)
  u16* Pw1 = Qs + (64 + wave * 16) * ATP;   // group-1 P
  short8 ones_f;
#pragma unroll
  for (int j = 0; j < 8; ++j) ones_f[j] = 0x3F80;  // bf16 1.0

  for (int half = 0; half < 2; ++half) {
    const int qb = half ? (15 - p) : p;
    const int q0 = qb * 128;
    const int nkt = 2 * qb + 2;
    // global addresses for K/V tile t
    auto kadr0 = [&](int t) { return Kg + (size_t)(64 * t + srow0) * 3072 + scol0; };
    auto vadr0 = [&](int t) { return Vtg + (size_t)srow0 * 2048 + 64 * t + scol0; };
    // ---- load Q 128x64 + K/V tile 0 into regs ----
    u16x8 qr0 = *(const u16x8*)(Qg + (size_t)(q0 + srow0) * 3072 + scol0);
    u16x8 qr1 = *(const u16x8*)(Qg + (size_t)(q0 + srow0 + 32) * 3072 + scol0);
    u16x8 qr2 = *(const u16x8*)(Qg + (size_t)(q0 + srow0 + 64) * 3072 + scol0);
    u16x8 qr3 = *(const u16x8*)(Qg + (size_t)(q0 + srow0 + 96) * 3072 + scol0);
    u16x8 kreg0 = *(const u16x8*)(kadr0(0));
    u16x8 kreg1 = *(const u16x8*)(kadr0(0) + 32 * 3072);
    u16x8 vreg0 = *(const u16x8*)(vadr0(0));
    u16x8 vreg1 = *(const u16x8*)(vadr0(0) + 32 * 2048);
    __syncthreads();  // previous q-tile's LDS reads (incl. P) complete
    *(u16x8*)&Qs[(size_t)srow0 * ATP + scol0] = qr0;
    *(u16x8*)&Qs[(size_t)(srow0 + 32) * ATP + scol0] = qr1;
    *(u16x8*)&Qs[(size_t)(srow0 + 64) * ATP + scol0] = qr2;
    *(u16x8*)&Qs[(size_t)(srow0 + 96) * ATP + scol0] = qr3;
    {
      u16* Kb = shm + 128 * ATP;  // buffer 0
      u16* Vb = Kb + 64 * ATP;
      *(u16x8*)&Kb[(size_t)srow0 * ATP + scol0] = kreg0;
      *(u16x8*)&Kb[(size_t)(srow0 + 32) * ATP + scol0] = kreg1;
      *(u16x8*)&Vb[(size_t)srow0 * ATP + scol0] = vreg0;
      *(u16x8*)&Vb[(size_t)(srow0 + 32) * ATP + scol0] = vreg1;
    }
    if (nkt > 1) {  // regs <- tile 1 (invariant: at iter kt, regs hold kt+1)
      kreg0 = *(const u16x8*)(kadr0(1));
      kreg1 = *(const u16x8*)(kadr0(1) + 32 * 3072);
      vreg0 = *(const u16x8*)(vadr0(1));
      vreg1 = *(const u16x8*)(vadr0(1) + 32 * 2048);
    }
    __syncthreads();  // buf0 + Q published
    // Q fragments for both groups (wave reads only its own P-alias rows)
    short8 qf0a = *(const short8*)&Qs[(wave * 16 + l16) * ATP + quad * 8];
    short8 qf1a = *(const short8*)&Qs[(wave * 16 + l16) * ATP + 32 + quad * 8];
    short8 qf0b = *(const short8*)&Qs[(64 + wave * 16 + l16) * ATP + quad * 8];
    short8 qf1b = *(const short8*)&Qs[(64 + wave * 16 + l16) * ATP + 32 + quad * 8];

    f32x4 lacc0 = {}, lacc1 = {};
    f32x4 o0[4] = {}, o1[4] = {};

    // g0mode: 0=full, 1=diag-mask, 2=skip. g1mask: diag-mask group 1.
    auto tile = [&](int kt, int g0mode, bool g1mask) {
      if (kt > 0) __syncthreads();  // reads of buf[(kt-1)&1] done;
                                    // writes of buf[kt&1] published
      if (kt + 1 < nkt) {  // stage tile kt+1 into idle buffer
        u16* Kw = shm + (128 + 128 * ((kt + 1) & 1)) * ATP;
        u16* Vw = Kw + 64 * ATP;
        *(u16x8*)&Kw[(size_t)srow0 * ATP + scol0] = kreg0;
        *(u16x8*)&Kw[(size_t)(srow0 + 32) * ATP + scol0] = kreg1;
        *(u16x8*)&Vw[(size_t)srow0 * ATP + scol0] = vreg0;
        *(u16x8*)&Vw[(size_t)(srow0 + 32) * ATP + scol0] = vreg1;
      }
      if (kt + 2 < nkt) {  // prefetch tile kt+2 into regs
        kreg0 = *(const u16x8*)(kadr0(kt + 2));
        kreg1 = *(const u16x8*)(kadr0(kt + 2) + 32 * 3072);
        vreg0 = *(const u16x8*)(vadr0(kt + 2));
        vreg1 = *(const u16x8*)(vadr0(kt + 2) + 32 * 2048);
      }
      const u16* Ks = shm + (128 + 128 * (kt & 1)) * ATP;
      const u16* Vs = Ks + 64 * ATP;

      // S^T = K . Q^T for both groups; kf fragments shared
      f32x4 s0[4] = {}, s1[4] = {};
#pragma unroll
      for (int mt = 0; mt < 4; ++mt) {
        short8 kf0 = *(const short8*)&Ks[(mt * 16 + l16) * ATP + quad * 8];
        short8 kf1 = *(const short8*)&Ks[(mt * 16 + l16) * ATP + 32 + quad * 8];
        if (g0mode < 2) {
          s0[mt] = mfma16(kf0, qf0a, s0[mt]);
          s0[mt] = mfma16(kf1, qf1a, s0[mt]);
        }
        s1[mt] = mfma16(kf0, qf0b, s1[mt]);
        s1[mt] = mfma16(kf1, qf1b, s1[mt]);
      }

      // softmax + P pack, group 0
      if (g0mode < 2) {
        const int qrow = q0 + wave * 16 + l16;
#pragma unroll
        for (int mt = 0; mt < 4; ++mt) {
          float pe[4];
#pragma unroll
          for (int r = 0; r < 4; ++r) {
            float pv = __builtin_amdgcn_exp2f(s0[mt][r]);
            if (g0mode == 1) {
              int kcol = kt * 64 + mt * 16 + quad * 4 + r;
              if (kcol > qrow) pv = 0.f;
            }
            pe[r] = pv;
          }
          u32 lo = __builtin_amdgcn_perm(__float_as_uint(pe[1]),
                                         __float_as_uint(pe[0]), 0x07060302u);
          u32 hi = __builtin_amdgcn_perm(__float_as_uint(pe[3]),
                                         __float_as_uint(pe[2]), 0x07060302u);
          uint2 pk = {lo, hi};
          *(uint2*)&Pw0[l16 * ATP + mt * 16 + quad * 4] = pk;
        }
      }
      // softmax + P pack, group 1
      {
        const int qrow = q0 + 64 + wave * 16 + l16;
#pragma unroll
        for (int mt = 0; mt < 4; ++mt) {
          float pe[4];
#pragma unroll
          for (int r = 0; r < 4; ++r) {
            float pv = __builtin_amdgcn_exp2f(s1[mt][r]);
            if (g1mask) {
              int kcol = kt * 64 + mt * 16 + quad * 4 + r;
              if (kcol > qrow) pv = 0.f;
            }
            pe[r] = pv;
          }
          u32 lo = __builtin_amdgcn_perm(__float_as_uint(pe[1]),
                                         __float_as_uint(pe[0]), 0x07060302u);
          u32 hi = __builtin_amdgcn_perm(__float_as_uint(pe[3]),
                                         __float_as_uint(pe[2]), 0x07060302u);
          uint2 pk = {lo, hi};
          *(uint2*)&Pw1[l16 * ATP + mt * 16 + quad * 4] = pk;
        }
      }

      // O += P.V ; l += P.1 — vf fragments shared between groups
#pragma unroll
      for (int ks = 0; ks < 2; ++ks) {
        short8 pf0, pf1;
        if (g0mode < 2) {
          pf0 = *(const short8*)&Pw0[l16 * ATP + ks * 32 + quad * 8];
          lacc0 = mfma16(pf0, ones_f, lacc0);
        }
        pf1 = *(const short8*)&Pw1[l16 * ATP + ks * 32 + quad * 8];
        lacc1 = mfma16(pf1, ones_f, lacc1);
#pragma unroll
        for (int dt = 0; dt < 4; ++dt) {
          short8 vf = *(const short8*)&Vs[(dt * 16 + l16) * ATP + ks * 32 + quad * 8];
          if (g0mode < 2) o0[dt] = mfma16(pf0, vf, o0[dt]);
          o1[dt] = mfma16(pf1, vf, o1[dt]);
        }
      }
    };

    for (int kt = 0; kt < nkt - 2; ++kt) tile(kt, 0, false);
    tile(nkt - 2, 1, false);  // group-0 diagonal; group 1 still full
    tile(nkt - 1, 2, true);   // group-1 diagonal; group 0 fully masked: skip

    // epilogue: lacc reg r = l for row quad*4+r — same rows as o[dt][r]
    size_t rb0 = (size_t)b * 2048 + q0 + wave * 16 + quad * 4;
#pragma unroll
    for (int r = 0; r < 4; ++r) {
      float inv = 1.f / lacc0[r];
#pragma unroll
      for (int dt = 0; dt < 4; ++dt)
        y[(rb0 + r) * 1024 + h * 64 + dt * 16 + l16] = f2bf(o0[dt][r] * inv);
    }
    size_t rb1 = rb0 + 64;
#pragma unroll
    for (int r = 0; r < 4; ++r) {
      float inv = 1.f / lacc1[r];
#pragma unroll
      for (int dt = 0; dt < 4; ++dt)
        y[(rb1 + r) * 1024 + h * 64 + dt * 16 + l16] = f2bf(o1[dt][r] * inv);
    }
  }
}

extern "C" void kernel_launch(void* const* d_in, const int* in_sizes, int n_in,
                              void* d_out, int out_size, void* d_ws, size_t ws_size,
                              hipStream_t stream) {
  const float* x = (const float*)d_in[0];
  const float* W_attn = (const float*)d_in[1];
  const float* b_attn = (const float*)d_in[2];
  const float* W_proj = (const float*)d_in[3];
  const float* b_proj = (const float*)d_in[4];
  float* out = (float*)d_out;
  char* ws = (char*)d_ws;
  u16* wta = (u16*)(ws + 16777216);    // W_attn^T bf16 [3072][1024]
  u16* wtp = (u16*)(ws + 23068672);    // W_proj^T bf16 [1024][1024]
  u16* qkv = (u16*)(ws + 25165824);    // qkv bf16 [8192][3072] (Q pre-scaled; V slice unused)
  u16* vt  = (u16*)(ws + 75497472);    // V^T bf16 [b][h][64][2048] (from gemm1 epilogue)
  u16* y   = (u16*)(ws + 92274688);    // attn out bf16 [8192][1024]

  k_prep<<<dim3(1024), 256, 0, stream>>>(W_attn, wta, W_proj, wtp);
  gemm_bt<1, 1, 1, 1><<<dim3(64, 24), 256, 0, stream>>>(nullptr, x, wta, b_attn, qkv, nullptr, vt, 8192, 3072, 1024);
  attn<<<dim3(8, 16, 4), 256, 0, stream>>>(qkv, vt, y);
  gemm_bt<0, 0, 0, 0><<<dim3(64, 8), 256, 0, stream>>>(y, nullptr, wtp, b_proj, nullptr, out, nullptr, 8192, 1024, 1024);
}

// Round 8
// 235.748 us; speedup vs baseline: 1.0682x; 1.0682x over previous
//
#include <hip/hip_runtime.h>

// B=4, T=2048, C=1024, H=16, D=64. fp32 in/out, bf16 internal compute.

typedef unsigned short u16;
typedef unsigned int u32;
typedef __attribute__((ext_vector_type(8))) unsigned short u16x8;
typedef __attribute__((ext_vector_type(4))) unsigned short u16x4;
typedef __attribute__((ext_vector_type(8))) short short8;
typedef __attribute__((ext_vector_type(4))) float f32x4;

__device__ inline u16 f2bf(float f) {
  unsigned u = __float_as_uint(f);
  u = (u + 0x7FFF + ((u >> 16) & 1)) >> 16;  // RNE
  return (u16)u;
}

__device__ inline f32x4 mfma16(short8 a, short8 b, f32x4 c) {
  return __builtin_amdgcn_mfma_f32_16x16x32_bf16(a, b, c, 0, 0, 0);
}

// ---------- fused prep: fp32->bf16 convert + two weight transposes ----------
// Blocks [0,8192): convert x (8192x1024 fp32 -> bf16), 1024 elems/block.
// Blocks [8192,8960): W_attn [1024][3072] -> wta [3072][1024] bf16.
// Blocks [8960,9216): W_proj [1024][1024] -> wtp [1024][1024] bf16.
__device__ inline void tw_tile(const float* __restrict__ in,
                               u16* __restrict__ outT, int R, int Cc,
                               int c0, int r0, int tid, u16 (*t)[65]) {
  int a = tid & 63, w = tid >> 6;
#pragma unroll
  for (int j = 0; j < 16; ++j) {
    int r = w + j * 4;
    t[r][a] = f2bf(in[(size_t)(r0 + r) * Cc + c0 + a]);
  }
  __syncthreads();
#pragma unroll
  for (int j = 0; j < 16; ++j) {
    int c = w + j * 4;
    outT[(size_t)(c0 + c) * R + r0 + a] = t[a][c];
  }
}

__global__ __launch_bounds__(256) void k_prep(const float* __restrict__ x,
                                              u16* __restrict__ xb,
                                              const float* __restrict__ Wa,
                                              u16* __restrict__ wta,
                                              const float* __restrict__ Wp,
                                              u16* __restrict__ wtp) {
  __shared__ u16 t[64][65];
  const int id = blockIdx.x, tid = threadIdx.x;
  if (id < 8192) {
    int i = (id * 256 + tid) * 4;
    float4 v = *(const float4*)(x + i);
    u16x4 o = {f2bf(v.x), f2bf(v.y), f2bf(v.z), f2bf(v.w)};
    *(u16x4*)(xb + i) = o;
  } else if (id < 8960) {
    int q = id - 8192;                      // 48 x 16 tiles
    tw_tile(Wa, wta, 1024, 3072, (q % 48) * 64, (q / 48) * 64, tid, t);
  } else {
    int q = id - 8960;                      // 16 x 16 tiles
    tw_tile(Wp, wtp, 1024, 1024, (q % 16) * 64, (q / 16) * 64, tid, t);
  }
}

// ---- bf16 GEMM: A[M][K] x Bt[N][K] + bias -> bf16 or fp32 out ----
// 128x128 block tile, BK=64, register-staged prefetch (proven structure;
// r7 showed fp32-A staging costs +27us — bf16 A from xb is the optimum).
// Block remap (bijective): XCD-chunk then 8-wide-m supertile.
// VT=1: columns >= 2048 (V slice of qkv) written directly transposed into
// vt[b][h][d][t] as packed u16x4; the qkv V-slice write is skipped.
template <int OUTBF, int QSCALE, int VT>
__global__ __launch_bounds__(256) void gemm_bt(const u16* __restrict__ A,
                                               const u16* __restrict__ Bt,
                                               const float* __restrict__ bias,
                                               u16* __restrict__ outb,
                                               float* __restrict__ outf,
                                               u16* __restrict__ vtout,
                                               int M, int N, int K) {
  __shared__ u16 As[128 * 64];
  __shared__ u16 Bs[128 * 64];
  const int nx = gridDim.x, ny = gridDim.y;
  int id0 = blockIdx.x + blockIdx.y * nx;
  int nwg = nx * ny;
  int q8 = nwg >> 3, x8 = id0 & 7, c8 = id0 >> 3;
  int id = x8 * q8 + c8;                    // nwg % 8 == 0 (bijective)
  int gs = 8 * ny, grp = id / gs, rem = id % gs;  // nx % 8 == 0
  const int m0 = (grp * 8 + (rem & 7)) * 128, n0 = (rem >> 3) * 128;

  const int tid = threadIdx.x, wave = tid >> 6, lane = tid & 63;
  const int quad = lane >> 4, l16 = lane & 15;
  const int wm = (wave & 1) * 64, wn = (wave >> 1) * 64;
  const int lrow = lane >> 3;      // 0..7 within the 8-row slab
  const int lch = lane & 7;        // global 16B chunk within the row
  const int slot = lch ^ lrow;     // swizzled LDS chunk slot
  const u16* sA[4];
  const u16* sB[4];
  int offA[4], offB[4];
#pragma unroll
  for (int j = 0; j < 4; ++j) {
    int r = wave * 32 + j * 8;     // slab base row (multiple of 8)
    sA[j] = A + (size_t)(m0 + r + lrow) * K + lch * 8;
    sB[j] = Bt + (size_t)(n0 + r + lrow) * K + lch * 8;
    offA[j] = (r + lrow) * 64 + slot * 8;
    offB[j] = offA[j];
  }
  // prologue: load tile 0 into regs
  u16x8 ra[4], rb[4];
#pragma unroll
  for (int j = 0; j < 4; ++j) {
    ra[j] = *(const u16x8*)(sA[j]);
    rb[j] = *(const u16x8*)(sB[j]);
  }
  f32x4 acc[4][4] = {};
  for (int kt = 0; kt < K; kt += 64) {
    __syncthreads();  // all waves done reading LDS tile kt-1
#pragma unroll
    for (int j = 0; j < 4; ++j) {
      *(u16x8*)&As[offA[j]] = ra[j];
      *(u16x8*)&Bs[offB[j]] = rb[j];
    }
    __syncthreads();
    if (kt + 64 < K) {  // prefetch tile kt+1 (latency hides under compute)
#pragma unroll
      for (int j = 0; j < 4; ++j) {
        ra[j] = *(const u16x8*)(sA[j] + kt + 64);
        rb[j] = *(const u16x8*)(sB[j] + kt + 64);
      }
    }
    const int sl = l16 & 7;
#pragma unroll
    for (int ks = 0; ks < 2; ++ks) {
      short8 af[4], bf[4];
#pragma unroll
      for (int mt = 0; mt < 4; ++mt)
        af[mt] = *(const short8*)(As + (wm + mt * 16 + l16) * 64 +
                                  ((ks * 4 + quad) ^ sl) * 8);
#pragma unroll
      for (int nt = 0; nt < 4; ++nt)
        bf[nt] = *(const short8*)(Bs + (wn + nt * 16 + l16) * 64 +
                                  ((ks * 4 + quad) ^ sl) * 8);
#pragma unroll
      for (int mt = 0; mt < 4; ++mt)
#pragma unroll
        for (int nt = 0; nt < 4; ++nt)
          acc[mt][nt] = mfma16(af[mt], bf[nt], acc[mt][nt]);
    }
  }
#pragma unroll
  for (int nt = 0; nt < 4; ++nt) {
    int col = n0 + wn + nt * 16 + l16;
    float bv = bias[col];
    if (VT && col >= 2048) {
      // V slice -> vt[(b*16+h)*64+d][t], hd = h*64+d = col-2048
      const int hd = col - 2048;
#pragma unroll
      for (int mt = 0; mt < 4; ++mt) {
        int rowb = m0 + wm + mt * 16 + quad * 4;  // global m, multiple of 4
        int bb = rowb >> 11, t0 = rowb & 2047;    // tile never crosses b
        u16x4 pk;
#pragma unroll
        for (int r = 0; r < 4; ++r) pk[r] = f2bf(acc[mt][nt][r] + bv);
        *(u16x4*)(vtout + ((size_t)(bb << 10) + hd) * 2048 + t0) = pk;
      }
    } else {
#pragma unroll
      for (int mt = 0; mt < 4; ++mt) {
        int rowb = m0 + wm + mt * 16 + quad * 4;
#pragma unroll
        for (int r = 0; r < 4; ++r) {
          float v = acc[mt][nt][r] + bv;
          if (QSCALE && col < 1024) v *= 0.18033688f;  // 0.125 * log2(e)
          if (OUTBF)
            outb[(size_t)(rowb + r) * N + col] = f2bf(v);
          else
            outf[(size_t)(rowb + r) * N + col] = v;
        }
      }
    }
  }
}

// ----------------- fused causal flash attention -------------------
// grid (8, H, B): block p handles 128-row q-tiles {p, 15-p} → uniform 34
// k-tiles/block, exactly 2 blocks/CU (proven optimum for this body).
// K/V double-buffered in LDS -> ONE barrier per k-tile (verified correct
// in r7; A/B vs r6's 2-barrier version this round). Per iter kt:
// [kt>0: barrier] retires reads of buf[(kt-1)&1] and publishes writes of
// buf[kt&1]; ds_write tile kt+1 into idle buffer; global-load tile kt+2;
// compute tile kt. LDS 55.3 KB -> still 2 blocks/CU.
// Each wave owns TWO 16-row q-groups; fixed-reference softmax (Q
// pre-scaled by 0.125*log2e in gemm1); l on the MFMA pipe (P·ones).
// Group-0 diagonal at nkt-2; skips nkt-1.
// LDS: P aliases the 128-row Q region (wave-private rows, in-order DS).
#define ATP 72  // LDS row stride (elems): 144B = 9x16B, conflict-light
__global__ __launch_bounds__(256) void attn(const u16* __restrict__ qkv,
                                            const u16* __restrict__ vt,
                                            u16* __restrict__ y) {
  __shared__ u16 shm[384 * ATP];  // 55.3 KB
  u16* Qs = shm;                  // 128 rows; aliased as P after frag reads
  // K/V buffers: buf b at rows 128+128b (K: 64 rows, then V: 64 rows)
  const int p = blockIdx.x, h = blockIdx.y, b = blockIdx.z;
  const int tid = threadIdx.x, wave = tid >> 6, lane = tid & 63;
  const int quad = lane >> 4, l16 = lane & 15;
  const u16* Qg = qkv + (size_t)b * 2048 * 3072 + h * 64;
  const u16* Kg = Qg + 1024;
  const u16* Vtg = vt + (size_t)(b * 16 + h) * 64 * 2048;
  const int srow0 = tid >> 3, scol0 = (tid & 7) * 8;  // srow0 in [0,32)
  u16* Pw0 = Qs + (wave * 16) * ATP;        // group-0 P (wave-private rows)
  u16* Pw1 = Qs + (64 + wave * 16) * ATP;   // group-1 P
  short8 ones_f;
#pragma unroll
  for (int j = 0; j < 8; ++j) ones_f[j] = 0x3F80;  // bf16 1.0

  for (int half = 0; half < 2; ++half) {
    const int qb = half ? (15 - p) : p;
    const int q0 = qb * 128;
    const int nkt = 2 * qb + 2;
    // global addresses for K/V tile t
    auto kadr0 = [&](int t) { return Kg + (size_t)(64 * t + srow0) * 3072 + scol0; };
    auto vadr0 = [&](int t) { return Vtg + (size_t)srow0 * 2048 + 64 * t + scol0; };
    // ---- load Q 128x64 + K/V tile 0 into regs ----
    u16x8 qr0 = *(const u16x8*)(Qg + (size_t)(q0 + srow0) * 3072 + scol0);
    u16x8 qr1 = *(const u16x8*)(Qg + (size_t)(q0 + srow0 + 32) * 3072 + scol0);
    u16x8 qr2 = *(const u16x8*)(Qg + (size_t)(q0 + srow0 + 64) * 3072 + scol0);
    u16x8 qr3 = *(const u16x8*)(Qg + (size_t)(q0 + srow0 + 96) * 3072 + scol0);
    u16x8 kreg0 = *(const u16x8*)(kadr0(0));
    u16x8 kreg1 = *(const u16x8*)(kadr0(0) + 32 * 3072);
    u16x8 vreg0 = *(const u16x8*)(vadr0(0));
    u16x8 vreg1 = *(const u16x8*)(vadr0(0) + 32 * 2048);
    __syncthreads();  // previous q-tile's LDS reads (incl. P) complete
    *(u16x8*)&Qs[(size_t)srow0 * ATP + scol0] = qr0;
    *(u16x8*)&Qs[(size_t)(srow0 + 32) * ATP + scol0] = qr1;
    *(u16x8*)&Qs[(size_t)(srow0 + 64) * ATP + scol0] = qr2;
    *(u16x8*)&Qs[(size_t)(srow0 + 96) * ATP + scol0] = qr3;
    {
      u16* Kb = shm + 128 * ATP;  // buffer 0
      u16* Vb = Kb + 64 * ATP;
      *(u16x8*)&Kb[(size_t)srow0 * ATP + scol0] = kreg0;
      *(u16x8*)&Kb[(size_t)(srow0 + 32) * ATP + scol0] = kreg1;
      *(u16x8*)&Vb[(size_t)srow0 * ATP + scol0] = vreg0;
      *(u16x8*)&Vb[(size_t)(srow0 + 32) * ATP + scol0] = vreg1;
    }
    if (nkt > 1) {  // regs <- tile 1 (invariant: at iter kt, regs hold kt+1)
      kreg0 = *(const u16x8*)(kadr0(1));
      kreg1 = *(const u16x8*)(kadr0(1) + 32 * 3072);
      vreg0 = *(const u16x8*)(vadr0(1));
      vreg1 = *(const u16x8*)(vadr0(1) + 32 * 2048);
    }
    __syncthreads();  // buf0 + Q published
    // Q fragments for both groups (wave reads only its own P-alias rows)
    short8 qf0a = *(const short8*)&Qs[(wave * 16 + l16) * ATP + quad * 8];
    short8 qf1a = *(const short8*)&Qs[(wave * 16 + l16) * ATP + 32 + quad * 8];
    short8 qf0b = *(const short8*)&Qs[(64 + wave * 16 + l16) * ATP + quad * 8];
    short8 qf1b = *(const short8*)&Qs[(64 + wave * 16 + l16) * ATP + 32 + quad * 8];

    f32x4 lacc0 = {}, lacc1 = {};
    f32x4 o0[4] = {}, o1[4] = {};

    // g0mode: 0=full, 1=diag-mask, 2=skip. g1mask: diag-mask group 1.
    auto tile = [&](int kt, int g0mode, bool g1mask) {
      if (kt > 0) __syncthreads();  // reads of buf[(kt-1)&1] done;
                                    // writes of buf[kt&1] published
      if (kt + 1 < nkt) {  // stage tile kt+1 into idle buffer
        u16* Kw = shm + (128 + 128 * ((kt + 1) & 1)) * ATP;
        u16* Vw = Kw + 64 * ATP;
        *(u16x8*)&Kw[(size_t)srow0 * ATP + scol0] = kreg0;
        *(u16x8*)&Kw[(size_t)(srow0 + 32) * ATP + scol0] = kreg1;
        *(u16x8*)&Vw[(size_t)srow0 * ATP + scol0] = vreg0;
        *(u16x8*)&Vw[(size_t)(srow0 + 32) * ATP + scol0] = vreg1;
      }
      if (kt + 2 < nkt) {  // prefetch tile kt+2 into regs
        kreg0 = *(const u16x8*)(kadr0(kt + 2));
        kreg1 = *(const u16x8*)(kadr0(kt + 2) + 32 * 3072);
        vreg0 = *(const u16x8*)(vadr0(kt + 2));
        vreg1 = *(const u16x8*)(vadr0(kt + 2) + 32 * 2048);
      }
      const u16* Ks = shm + (128 + 128 * (kt & 1)) * ATP;
      const u16* Vs = Ks + 64 * ATP;

      // S^T = K . Q^T for both groups; kf fragments shared
      f32x4 s0[4] = {}, s1[4] = {};
#pragma unroll
      for (int mt = 0; mt < 4; ++mt) {
        short8 kf0 = *(const short8*)&Ks[(mt * 16 + l16) * ATP + quad * 8];
        short8 kf1 = *(const short8*)&Ks[(mt * 16 + l16) * ATP + 32 + quad * 8];
        if (g0mode < 2) {
          s0[mt] = mfma16(kf0, qf0a, s0[mt]);
          s0[mt] = mfma16(kf1, qf1a, s0[mt]);
        }
        s1[mt] = mfma16(kf0, qf0b, s1[mt]);
        s1[mt] = mfma16(kf1, qf1b, s1[mt]);
      }

      // softmax + P pack, group 0
      if (g0mode < 2) {
        const int qrow = q0 + wave * 16 + l16;
#pragma unroll
        for (int mt = 0; mt < 4; ++mt) {
          float pe[4];
#pragma unroll
          for (int r = 0; r < 4; ++r) {
            float pv = __builtin_amdgcn_exp2f(s0[mt][r]);
            if (g0mode == 1) {
              int kcol = kt * 64 + mt * 16 + quad * 4 + r;
              if (kcol > qrow) pv = 0.f;
            }
            pe[r] = pv;
          }
          u32 lo = __builtin_amdgcn_perm(__float_as_uint(pe[1]),
                                         __float_as_uint(pe[0]), 0x07060302u);
          u32 hi = __builtin_amdgcn_perm(__float_as_uint(pe[3]),
                                         __float_as_uint(pe[2]), 0x07060302u);
          uint2 pk = {lo, hi};
          *(uint2*)&Pw0[l16 * ATP + mt * 16 + quad * 4] = pk;
        }
      }
      // softmax + P pack, group 1
      {
        const int qrow = q0 + 64 + wave * 16 + l16;
#pragma unroll
        for (int mt = 0; mt < 4; ++mt) {
          float pe[4];
#pragma unroll
          for (int r = 0; r < 4; ++r) {
            float pv = __builtin_amdgcn_exp2f(s1[mt][r]);
            if (g1mask) {
              int kcol = kt * 64 + mt * 16 + quad * 4 + r;
              if (kcol > qrow) pv = 0.f;
            }
            pe[r] = pv;
          }
          u32 lo = __builtin_amdgcn_perm(__float_as_uint(pe[1]),
                                         __float_as_uint(pe[0]), 0x07060302u);
          u32 hi = __builtin_amdgcn_perm(__float_as_uint(pe[3]),
                                         __float_as_uint(pe[2]), 0x07060302u);
          uint2 pk = {lo, hi};
          *(uint2*)&Pw1[l16 * ATP + mt * 16 + quad * 4] = pk;
        }
      }

      // O += P.V ; l += P.1 — vf fragments shared between groups
#pragma unroll
      for (int ks = 0; ks < 2; ++ks) {
        short8 pf0, pf1;
        if (g0mode < 2) {
          pf0 = *(const short8*)&Pw0[l16 * ATP + ks * 32 + quad * 8];
          lacc0 = mfma16(pf0, ones_f, lacc0);
        }
        pf1 = *(const short8*)&Pw1[l16 * ATP + ks * 32 + quad * 8];
        lacc1 = mfma16(pf1, ones_f, lacc1);
#pragma unroll
        for (int dt = 0; dt < 4; ++dt) {
          short8 vf = *(const short8*)&Vs[(dt * 16 + l16) * ATP + ks * 32 + quad * 8];
          if (g0mode < 2) o0[dt] = mfma16(pf0, vf, o0[dt]);
          o1[dt] = mfma16(pf1, vf, o1[dt]);
        }
      }
    };

    for (int kt = 0; kt < nkt - 2; ++kt) tile(kt, 0, false);
    tile(nkt - 2, 1, false);  // group-0 diagonal; group 1 still full
    tile(nkt - 1, 2, true);   // group-1 diagonal; group 0 fully masked: skip

    // epilogue: lacc reg r = l for row quad*4+r — same rows as o[dt][r]
    size_t rb0 = (size_t)b * 2048 + q0 + wave * 16 + quad * 4;
#pragma unroll
    for (int r = 0; r < 4; ++r) {
      float inv = 1.f / lacc0[r];
#pragma unroll
      for (int dt = 0; dt < 4; ++dt)
        y[(rb0 + r) * 1024 + h * 64 + dt * 16 + l16] = f2bf(o0[dt][r] * inv);
    }
    size_t rb1 = rb0 + 64;
#pragma unroll
    for (int r = 0; r < 4; ++r) {
      float inv = 1.f / lacc1[r];
#pragma unroll
      for (int dt = 0; dt < 4; ++dt)
        y[(rb1 + r) * 1024 + h * 64 + dt * 16 + l16] = f2bf(o1[dt][r] * inv);
    }
  }
}

extern "C" void kernel_launch(void* const* d_in, const int* in_sizes, int n_in,
                              void* d_out, int out_size, void* d_ws, size_t ws_size,
                              hipStream_t stream) {
  const float* x = (const float*)d_in[0];
  const float* W_attn = (const float*)d_in[1];
  const float* b_attn = (const float*)d_in[2];
  const float* W_proj = (const float*)d_in[3];
  const float* b_proj = (const float*)d_in[4];
  float* out = (float*)d_out;
  char* ws = (char*)d_ws;
  u16* xb  = (u16*)(ws);               // x as bf16 [8192][1024]
  u16* wta = (u16*)(ws + 16777216);    // W_attn^T bf16 [3072][1024]
  u16* wtp = (u16*)(ws + 23068672);    // W_proj^T bf16 [1024][1024]
  u16* qkv = (u16*)(ws + 25165824);    // qkv bf16 [8192][3072] (Q pre-scaled; V slice unused)
  u16* vt  = (u16*)(ws + 75497472);    // V^T bf16 [b][h][64][2048] (from gemm1 epilogue)
  u16* y   = (u16*)(ws + 92274688);    // attn out bf16 [8192][1024]

  k_prep<<<dim3(9216), 256, 0, stream>>>(x, xb, W_attn, wta, W_proj, wtp);
  gemm_bt<1, 1, 1><<<dim3(64, 24), 256, 0, stream>>>(xb, wta, b_attn, qkv, nullptr, vt, 8192, 3072, 1024);
  attn<<<dim3(8, 16, 4), 256, 0, stream>>>(qkv, vt, y);
  gemm_bt<0, 0, 0><<<dim3(64, 8), 256, 0, stream>>>(y, wtp, b_proj, nullptr, out, nullptr, 8192, 1024, 1024);
}